// Round 2
// baseline (733.957 us; speedup 1.0000x reference)
//
#include <hip/hip_runtime.h>
#include <hip/hip_bf16.h>

#define B_ 2
#define S_ 2048
#define D_ 2048
#define H_ 16
#define HD_ 128

typedef __attribute__((ext_vector_type(4))) float f32x4;
typedef __attribute__((ext_vector_type(8))) short bf16x8;

static __device__ __forceinline__ unsigned short f2bf(float f) {
    unsigned int u = __float_as_uint(f);
    u += 0x7fffu + ((u >> 16) & 1u);
    return (unsigned short)(u >> 16);
}
static __device__ __forceinline__ float bf2f(unsigned short h) {
    return __uint_as_float(((unsigned int)h) << 16);
}

#define MFMA_K32(a, b, c) __builtin_amdgcn_mfma_f32_16x16x32_bf16(a, b, c, 0, 0, 0)

// ---------------- weight fp32 -> bf16 ----------------
__global__ void cvt_f32_bf16(const float4* __restrict__ src,
                             ushort4* __restrict__ dst, int n4) {
    int i = blockIdx.x * blockDim.x + threadIdx.x;
    if (i < n4) {
        float4 v = src[i];
        ushort4 o;
        o.x = f2bf(v.x); o.y = f2bf(v.y); o.z = f2bf(v.z); o.w = f2bf(v.w);
        dst[i] = o;
    }
}

// ---------------- GEMM: C[m][n] = sum_k A[m][k] * W[n][k] ----------------
// A: fp32 or bf16, [M=4096, K=2048] row-major. W: bf16 [N=2048, K=2048] row-major.
// OUT_HEADED: C -> bf16 [B,H,S,HD]   else: C -> fp32 [M,N] row-major.
template<bool A_BF16, bool OUT_HEADED>
__global__ void gemm_xwt(const void* __restrict__ Aptr,
                         const unsigned short* __restrict__ W,
                         void* __restrict__ Cptr) {
    constexpr int K = D_, N = D_;
    constexpr int LDT = 40;  // padded LDS stride (elements)
    __shared__ unsigned short As[128 * LDT];
    __shared__ unsigned short Ws[128 * LDT];

    const int tid = threadIdx.x;
    const int lane = tid & 63;
    const int wid = tid >> 6;
    const int wy = wid >> 1, wx = wid & 1;   // 2x2 wave grid, 64x64 each
    const int bm = blockIdx.x * 128;
    const int bn = blockIdx.y * 128;

    const int sr = tid >> 1;            // staging row 0..127
    const int sc = (tid & 1) * 16;      // staging col base 0/16

    const int lr = lane & 15;
    const int lk = (lane >> 4) * 8;

    f32x4 acc[4][4] = {};

    for (int k0 = 0; k0 < K; k0 += 32) {
        __syncthreads();
        // ---- stage A tile [128][32] ----
        if constexpr (A_BF16) {
            const unsigned short* Ag = (const unsigned short*)Aptr;
            const size_t base = (size_t)(bm + sr) * K + k0 + sc;
            bf16x8 v0 = *(const bf16x8*)(Ag + base);
            bf16x8 v1 = *(const bf16x8*)(Ag + base + 8);
            *(bf16x8*)&As[sr * LDT + sc] = v0;
            *(bf16x8*)&As[sr * LDT + sc + 8] = v1;
        } else {
            const float* Ag = (const float*)Aptr;
            const size_t base = (size_t)(bm + sr) * K + k0 + sc;
            #pragma unroll
            for (int i = 0; i < 2; ++i) {
                float4 f0 = *(const float4*)(Ag + base + i * 8);
                float4 f1 = *(const float4*)(Ag + base + i * 8 + 4);
                bf16x8 pv;
                pv[0] = (short)f2bf(f0.x); pv[1] = (short)f2bf(f0.y);
                pv[2] = (short)f2bf(f0.z); pv[3] = (short)f2bf(f0.w);
                pv[4] = (short)f2bf(f1.x); pv[5] = (short)f2bf(f1.y);
                pv[6] = (short)f2bf(f1.z); pv[7] = (short)f2bf(f1.w);
                *(bf16x8*)&As[sr * LDT + sc + i * 8] = pv;
            }
        }
        // ---- stage W tile [128][32] ----
        {
            const size_t base = (size_t)(bn + sr) * K + k0 + sc;
            bf16x8 v0 = *(const bf16x8*)(W + base);
            bf16x8 v1 = *(const bf16x8*)(W + base + 8);
            *(bf16x8*)&Ws[sr * LDT + sc] = v0;
            *(bf16x8*)&Ws[sr * LDT + sc + 8] = v1;
        }
        __syncthreads();

        bf16x8 af[4], wf[4];
        #pragma unroll
        for (int i = 0; i < 4; ++i)
            af[i] = *(const bf16x8*)&As[(wy * 64 + i * 16 + lr) * LDT + lk];
        #pragma unroll
        for (int i = 0; i < 4; ++i)
            wf[i] = *(const bf16x8*)&Ws[(wx * 64 + i * 16 + lr) * LDT + lk];
        #pragma unroll
        for (int mi = 0; mi < 4; ++mi)
            #pragma unroll
            for (int ni = 0; ni < 4; ++ni)
                acc[mi][ni] = MFMA_K32(af[mi], wf[ni], acc[mi][ni]);
    }

    // ---- epilogue: C/D layout col = lane&15, row = (lane>>4)*4 + reg ----
    #pragma unroll
    for (int mi = 0; mi < 4; ++mi) {
        #pragma unroll
        for (int ni = 0; ni < 4; ++ni) {
            #pragma unroll
            for (int rg = 0; rg < 4; ++rg) {
                int m = bm + wy * 64 + mi * 16 + (lane >> 4) * 4 + rg;
                int n = bn + wx * 64 + ni * 16 + lr;
                float val = acc[mi][ni][rg];
                if constexpr (OUT_HEADED) {
                    int b = m >> 11, s = m & (S_ - 1);
                    int h = n >> 7, dd = n & (HD_ - 1);
                    ((unsigned short*)Cptr)[(((size_t)(b * H_ + h) * S_) + s) * HD_ + dd] =
                        f2bf(val);
                } else {
                    ((float*)Cptr)[(size_t)m * N + n] = val;
                }
            }
        }
    }
}

// ---------------- causal flash attention ----------------
// Q,K,V: bf16 [B,H,S,HD]; O: bf16 [B,S,H*HD]
// block = 256 thr (4 waves), 64 Q rows per block (16/wave), KV tile = 32.
// K rows are staged PERMUTED in LDS (kv -> pos p) so that the QK^T output
// fragment (slot f,rg on lane group g) holds kv = 8g+4f+rg, which is exactly
// the 16x16x32 MFMA A-fragment layout (k = g*8 + j, j = f*4+rg) for PV.
__global__ void attn_fwd(const unsigned short* __restrict__ Qg,
                         const unsigned short* __restrict__ Kg,
                         const unsigned short* __restrict__ Vg,
                         unsigned short* __restrict__ Og) {
    constexpr int KB = 32;
    constexpr int VST = 40;                  // padded Vt stride (16B-aligned rows)
    __shared__ unsigned short Ks[KB * HD_];  // [32][128], XOR-swizzled rows, kv-permuted
    __shared__ unsigned short Vt[HD_ * VST]; // transposed [128][40]

    const int tid = threadIdx.x;
    const int lane = tid & 63;
    const int w = tid >> 6;
    const int g = lane >> 4;
    const int lr = lane & 15;

    const int bh = blockIdx.y;           // b*H + h
    const int q0 = blockIdx.x * 64;
    const size_t base = (size_t)bh * S_ * HD_;

    const int qr = q0 + w * 16 + lr;     // this lane's Q row (as S^T column)

    // Q fragments (B-operand layout), pre-scaled by 1/sqrt(HD)
    bf16x8 qf[4];
    #pragma unroll
    for (int st = 0; st < 4; ++st) {
        bf16x8 t = *(const bf16x8*)(Qg + base + (size_t)qr * HD_ + st * 32 + g * 8);
        #pragma unroll
        for (int j = 0; j < 8; ++j)
            t[j] = (short)f2bf(bf2f((unsigned short)t[j]) * 0.08838834764831845f);
        qf[st] = t;
    }

    float m_r = -1e30f, l_r = 0.0f;
    f32x4 accO[8] = {};

    const int wq0 = q0 + w * 16;
    const int ntiles = (q0 + 64) / KB;

    for (int t = 0; t < ntiles; ++t) {
        const int k0 = t * KB;
        __syncthreads();
        // ---- stage K (permuted+swizzled) and V (transposed) tiles ----
        #pragma unroll
        for (int cc = 0; cc < 2; ++cc) {
            int c = tid + cc * 256;          // 0..511
            int vr = c >> 4;                 // kv row 0..31
            int d8 = (c & 15) * 8;           // d chunk
            // permuted position: kv bits [b4 b3 b2 b1 b0] -> p = [b2 b4 b3 b1 b0]
            int pr = (vr & 3) | (((vr >> 3) & 3) << 2) | (((vr >> 2) & 1) << 4);
            bf16x8 kv = *(const bf16x8*)(Kg + base + (size_t)(k0 + vr) * HD_ + d8);
            int bo = (pr * 256 + d8 * 2) ^ ((pr & 7) << 4);
            *(bf16x8*)((char*)Ks + bo) = kv;
            bf16x8 vv = *(const bf16x8*)(Vg + base + (size_t)(k0 + vr) * HD_ + d8);
            #pragma unroll
            for (int j = 0; j < 8; ++j)
                Vt[(d8 + j) * VST + vr] = (unsigned short)vv[j];
        }
        __syncthreads();

        if (k0 > wq0 + 15) continue;  // tile fully masked for this wave

        // ---- S^T = K · Q^T (positions permuted; lane slot (f,rg) = kv 8g+4f+rg) ----
        f32x4 sf[2] = {};
        #pragma unroll
        for (int f = 0; f < 2; ++f) {
            int row = f * 16 + lr;
            #pragma unroll
            for (int st = 0; st < 4; ++st) {
                int bo = (row * 256 + st * 64 + g * 16) ^ ((row & 7) << 4);
                bf16x8 kf = *(const bf16x8*)((char*)Ks + bo);
                sf[f] = MFMA_K32(kf, qf[st], sf[f]);
            }
        }

        if (k0 + KB - 1 > wq0) {  // boundary tile: causal mask (permuted kv mapping)
            #pragma unroll
            for (int f = 0; f < 2; ++f)
                #pragma unroll
                for (int rg = 0; rg < 4; ++rg)
                    if (k0 + 8 * g + 4 * f + rg > qr) sf[f][rg] = -1e30f;
        }

        // ---- online softmax (row = this lane's qr) ----
        float pm = -1e30f;
        #pragma unroll
        for (int f = 0; f < 2; ++f)
            #pragma unroll
            for (int rg = 0; rg < 4; ++rg) pm = fmaxf(pm, sf[f][rg]);
        pm = fmaxf(pm, __shfl_xor(pm, 16));
        pm = fmaxf(pm, __shfl_xor(pm, 32));
        float mnew = fmaxf(m_r, pm);
        float corr = __expf(m_r - mnew);
        m_r = mnew;

        float ls = 0.0f;
        bf16x8 pa8;
        #pragma unroll
        for (int f = 0; f < 2; ++f) {
            #pragma unroll
            for (int rg = 0; rg < 4; ++rg) {
                float p = __expf(sf[f][rg] - mnew);
                ls += p;
                pa8[f * 4 + rg] = (short)f2bf(p);
            }
        }
        ls += __shfl_xor(ls, 16);
        ls += __shfl_xor(ls, 32);
        l_r = l_r * corr + ls;

        // O rescale: accO reg j holds qrow g*4+j -> fetch its corr via shfl
        float cj[4];
        #pragma unroll
        for (int j = 0; j < 4; ++j) cj[j] = __shfl(corr, g * 4 + j);
        #pragma unroll
        for (int db = 0; db < 8; ++db) {
            accO[db][0] *= cj[0]; accO[db][1] *= cj[1];
            accO[db][2] *= cj[2]; accO[db][3] *= cj[3];
        }

        // ---- PV: pa8 is a valid 16x16x32 A-fragment; Vt rows are B-fragments ----
        #pragma unroll
        for (int db = 0; db < 8; ++db) {
            bf16x8 vb = *(const bf16x8*)&Vt[(db * 16 + lr) * VST + g * 8];
            accO[db] = MFMA_K32(pa8, vb, accO[db]);
        }
    }

    // ---- epilogue: divide by l, store to [B,S,H*HD] bf16 ----
    float lj[4];
    #pragma unroll
    for (int j = 0; j < 4; ++j) lj[j] = __shfl(l_r, g * 4 + j);
    const int b = bh >> 4, h = bh & (H_ - 1);
    #pragma unroll
    for (int j = 0; j < 4; ++j) {
        int qq = q0 + w * 16 + g * 4 + j;
        float inv = 1.0f / lj[j];
        unsigned short* dst = Og + ((size_t)(b * S_ + qq)) * D_ + h * HD_;
        #pragma unroll
        for (int db = 0; db < 8; ++db)
            dst[db * 16 + lr] = f2bf(accO[db][j] * inv);
    }
}

extern "C" void kernel_launch(void* const* d_in, const int* in_sizes, int n_in,
                              void* d_out, int out_size, void* d_ws, size_t ws_size,
                              hipStream_t stream) {
    const float* q  = (const float*)d_in[0];
    const float* k  = (const float*)d_in[1];
    const float* v  = (const float*)d_in[2];
    const float* wq = (const float*)d_in[3];
    const float* wk = (const float*)d_in[4];
    const float* wv = (const float*)d_in[5];
    const float* wo = (const float*)d_in[6];

    unsigned short* ws  = (unsigned short*)d_ws;
    unsigned short* wqb = ws;
    unsigned short* wkb = wqb + (size_t)D_ * D_;
    unsigned short* wvb = wkb + (size_t)D_ * D_;
    unsigned short* wob = wvb + (size_t)D_ * D_;
    unsigned short* xq  = wob + (size_t)D_ * D_;
    unsigned short* xk  = xq + (size_t)B_ * S_ * D_;
    unsigned short* xv  = xk + (size_t)B_ * S_ * D_;
    unsigned short* ao  = xv + (size_t)B_ * S_ * D_;

    const int n4 = D_ * D_ / 4;
    const int cvb = (n4 + 255) / 256;
    cvt_f32_bf16<<<cvb, 256, 0, stream>>>((const float4*)wq, (ushort4*)wqb, n4);
    cvt_f32_bf16<<<cvb, 256, 0, stream>>>((const float4*)wk, (ushort4*)wkb, n4);
    cvt_f32_bf16<<<cvb, 256, 0, stream>>>((const float4*)wv, (ushort4*)wvb, n4);
    cvt_f32_bf16<<<cvb, 256, 0, stream>>>((const float4*)wo, (ushort4*)wob, n4);

    dim3 gg(B_ * S_ / 128, D_ / 128);
    gemm_xwt<false, true><<<gg, 256, 0, stream>>>(q, wqb, xq);
    gemm_xwt<false, true><<<gg, 256, 0, stream>>>(k, wkb, xk);
    gemm_xwt<false, true><<<gg, 256, 0, stream>>>(v, wvb, xv);

    dim3 ga(S_ / 64, B_ * H_);
    attn_fwd<<<ga, 256, 0, stream>>>(xq, xk, xv, ao);

    gemm_xwt<true, false><<<gg, 256, 0, stream>>>(ao, wob, d_out);
}

// Round 3
// 327.756 us; speedup vs baseline: 2.2393x; 2.2393x over previous
//
#include <hip/hip_runtime.h>
#include <hip/hip_bf16.h>

#define B_ 2
#define S_ 2048
#define D_ 2048
#define H_ 16
#define HD_ 128

typedef __attribute__((ext_vector_type(4))) float f32x4;
typedef __attribute__((ext_vector_type(8))) short bf16x8;

static __device__ __forceinline__ unsigned short f2bf(float f) {
    unsigned int u = __float_as_uint(f);
    u += 0x7fffu + ((u >> 16) & 1u);
    return (unsigned short)(u >> 16);
}
static __device__ __forceinline__ float bf2f(unsigned short h) {
    return __uint_as_float(((unsigned int)h) << 16);
}

#define MFMA_K32(a, b, c) __builtin_amdgcn_mfma_f32_16x16x32_bf16(a, b, c, 0, 0, 0)

// async global->LDS, 16B per lane. LDS dest must be wave-uniform base; HW adds lane*16.
static __device__ __forceinline__ void gll16(const void* g, void* l) {
    __builtin_amdgcn_global_load_lds((const __attribute__((address_space(1))) void*)g,
                                     (__attribute__((address_space(3))) void*)l,
                                     16, 0, 0);
}

// ---------------- fp32 -> bf16 converters ----------------
__global__ void cvt_in(const float4* __restrict__ src, ushort4* __restrict__ dst) {
    int i = blockIdx.x * 256 + threadIdx.x;
    float4 v = src[i];
    ushort4 o;
    o.x = f2bf(v.x); o.y = f2bf(v.y); o.z = f2bf(v.z); o.w = f2bf(v.w);
    dst[i] = o;
}

__global__ void cvt_w4(const float4* __restrict__ s0, ushort4* __restrict__ d0,
                       const float4* __restrict__ s1, ushort4* __restrict__ d1,
                       const float4* __restrict__ s2, ushort4* __restrict__ d2,
                       const float4* __restrict__ s3, ushort4* __restrict__ d3) {
    const float4* s; ushort4* d;
    switch (blockIdx.y) {
        case 0: s = s0; d = d0; break;
        case 1: s = s1; d = d1; break;
        case 2: s = s2; d = d2; break;
        default: s = s3; d = d3; break;
    }
    int i = blockIdx.x * 256 + threadIdx.x;
    float4 v = s[i];
    ushort4 o;
    o.x = f2bf(v.x); o.y = f2bf(v.y); o.z = f2bf(v.z); o.w = f2bf(v.w);
    d[i] = o;
}

// ---------------- GEMM: C[m][n] = sum_k A[m][k] * W[n][k] ----------------
// A bf16 [4096,2048] row-major, W bf16 [2048,2048] row-major. m97 structure:
// 128x128 tile, BK=32, global_load_lds width16, linear LDS, 4 waves 2x2.
// OUT_MODE: 0 = bf16 headed [B,H,S,HD] (Q)
//           1 = K tiles: per (bh, s>>6): row pr(vr) permuted, 16B-chunk XOR swizzle
//           2 = V tiles: per (bh, s>>6): [d][kchunk^(d&7)] transposed-swizzled
//           3 = fp32 plain [M,N] (final output)
template<int OUT_MODE>
__global__ __launch_bounds__(256) void gemm_xwt(
        const unsigned short* __restrict__ A,
        const unsigned short* __restrict__ W,
        void* __restrict__ C) {
    constexpr int K = D_;
    __shared__ unsigned short As[128 * 32];
    __shared__ unsigned short Ws[128 * 32];
    const int tid = threadIdx.x, lane = tid & 63, wid = tid >> 6;
    const int wy = wid >> 1, wx = wid & 1;
    const int g = lane >> 4, lr = lane & 15;
    const int swz = (blockIdx.x & 7) * 64 + (blockIdx.x >> 3);  // XCD-aware, bijective (512%8==0)
    const int bm = (swz & 31) * 128;
    const int bn = (swz >> 5) * 128;

    const int ch0 = wid * 128 + lane;           // staging chunk ids
    const int r0 = ch0 >> 2, c0 = (ch0 & 3) * 8;
    const int ch1 = ch0 + 64;
    const int r1 = ch1 >> 2, c1 = (ch1 & 3) * 8;

    f32x4 acc[4][4] = {};
    for (int k0 = 0; k0 < K; k0 += 32) {
        __syncthreads();
        gll16(A + (size_t)(bm + r0) * K + k0 + c0, (char*)As + wid * 2048);
        gll16(A + (size_t)(bm + r1) * K + k0 + c1, (char*)As + wid * 2048 + 1024);
        gll16(W + (size_t)(bn + r0) * K + k0 + c0, (char*)Ws + wid * 2048);
        gll16(W + (size_t)(bn + r1) * K + k0 + c1, (char*)Ws + wid * 2048 + 1024);
        __syncthreads();
        bf16x8 af[4], wf[4];
        #pragma unroll
        for (int i = 0; i < 4; ++i)
            af[i] = *(const bf16x8*)((const char*)As + (wy * 64 + i * 16 + lr) * 64 + g * 16);
        #pragma unroll
        for (int i = 0; i < 4; ++i)
            wf[i] = *(const bf16x8*)((const char*)Ws + (wx * 64 + i * 16 + lr) * 64 + g * 16);
        #pragma unroll
        for (int mi = 0; mi < 4; ++mi)
            #pragma unroll
            for (int ni = 0; ni < 4; ++ni)
                acc[mi][ni] = MFMA_K32(af[mi], wf[ni], acc[mi][ni]);
    }

    #pragma unroll
    for (int mi = 0; mi < 4; ++mi) {
        #pragma unroll
        for (int ni = 0; ni < 4; ++ni) {
            const int n = bn + wx * 64 + ni * 16 + lr;
            const int m0 = bm + wy * 64 + mi * 16 + g * 4;
            if constexpr (OUT_MODE == 0) {
                #pragma unroll
                for (int rg = 0; rg < 4; ++rg) {
                    int m = m0 + rg;
                    int bb = m >> 11, s = m & (S_ - 1);
                    int hh = n >> 7, dd = n & (HD_ - 1);
                    ((unsigned short*)C)[(((size_t)(bb * H_ + hh) * S_) + s) * HD_ + dd] =
                        f2bf(acc[mi][ni][rg]);
                }
            } else if constexpr (OUT_MODE == 1) {
                #pragma unroll
                for (int rg = 0; rg < 4; ++rg) {
                    int m = m0 + rg;
                    int bb = m >> 11, s = m & (S_ - 1);
                    int hh = n >> 7, dd = n & (HD_ - 1);
                    int vr = s & 63;
                    int pr = (vr & 3) | (((vr >> 3) & 3) << 2) | (((vr >> 2) & 1) << 4) | (vr & 32);
                    size_t eo = ((size_t)(bb * H_ + hh) << 18) + ((size_t)(s >> 6) << 13)
                              + pr * 128 + (((((unsigned)dd) << 1) ^ ((pr & 7) << 4)) >> 1);
                    ((unsigned short*)C)[eo] = f2bf(acc[mi][ni][rg]);
                }
            } else if constexpr (OUT_MODE == 2) {
                int bb = m0 >> 11, s0 = m0 & (S_ - 1);
                int hh = n >> 7, dd = n & (HD_ - 1);
                int ch = ((s0 & 63) >> 3) ^ (dd & 7);
                size_t eo = ((size_t)(bb * H_ + hh) << 18) + ((size_t)(s0 >> 6) << 13)
                          + dd * 64 + (ch << 3) + (s0 & 7);
                ushort4 pk;
                pk.x = f2bf(acc[mi][ni][0]); pk.y = f2bf(acc[mi][ni][1]);
                pk.z = f2bf(acc[mi][ni][2]); pk.w = f2bf(acc[mi][ni][3]);
                *(ushort4*)&((unsigned short*)C)[eo] = pk;
            } else {
                #pragma unroll
                for (int rg = 0; rg < 4; ++rg)
                    ((float*)C)[(size_t)(m0 + rg) * D_ + n] = acc[mi][ni][rg];
            }
        }
    }
}

// ---------------- causal flash attention ----------------
// Q: bf16 [B,H,S,HD]. Kt/Vt: pre-transformed 64-row tiles (see GEMM epilogues).
// O: bf16 [B,S,H*HD]. 4 waves x 16 q-rows = 64 q-rows per tile; KVBLK=64.
// Block processes q-tiles qi and 31-qi -> uniform 33 KV-tiles per block.
__global__ __launch_bounds__(256) void attn_fwd(
        const unsigned short* __restrict__ Qg,
        const unsigned short* __restrict__ Kt,
        const unsigned short* __restrict__ Vt,
        unsigned short* __restrict__ Og) {
    __shared__ char Ks[16384];  // 64 rows x 256B (permuted+swizzled)
    __shared__ char Vs[16384];  // 128 d-rows x 128B (k-chunk swizzled)
    const int tid = threadIdx.x, lane = tid & 63, w = tid >> 6;
    const int g = lane >> 4, lr = lane & 15;
    const int swz = (blockIdx.x & 7) * 64 + (blockIdx.x >> 3);  // 4 heads per XCD
    const int bh = swz >> 4, qi = swz & 15;
    const int b = bh >> 4, h = bh & (H_ - 1);
    const size_t base = (size_t)bh * S_ * HD_;

    #pragma unroll 1
    for (int half = 0; half < 2; ++half) {
        const int q0 = (half ? (31 - qi) : qi) * 64;
        const int qr = q0 + w * 16 + lr;
        bf16x8 qf[4];
        #pragma unroll
        for (int st = 0; st < 4; ++st) {
            bf16x8 t = *(const bf16x8*)(Qg + base + (size_t)qr * HD_ + st * 32 + g * 8);
            #pragma unroll
            for (int j = 0; j < 8; ++j)
                t[j] = (short)f2bf(bf2f((unsigned short)t[j]) * 0.08838834764831845f);
            qf[st] = t;
        }
        float m_r = -1e30f, l_r = 0.0f;
        f32x4 accO[8] = {};
        const int nt = (q0 >> 6) + 1;
        for (int t = 0; t < nt; ++t) {
            __syncthreads();
            const size_t tb = base + (size_t)t * 8192 + w * 2048 + lane * 8;
            gll16(Kt + tb,        Ks + w * 4096);
            gll16(Kt + tb + 512,  Ks + w * 4096 + 1024);
            gll16(Kt + tb + 1024, Ks + w * 4096 + 2048);
            gll16(Kt + tb + 1536, Ks + w * 4096 + 3072);
            gll16(Vt + tb,        Vs + w * 4096);
            gll16(Vt + tb + 512,  Vs + w * 4096 + 1024);
            gll16(Vt + tb + 1024, Vs + w * 4096 + 2048);
            gll16(Vt + tb + 1536, Vs + w * 4096 + 3072);
            __syncthreads();

            // S^T = Kperm . Q^T : slot (f,g,rg) holds kv = 32*(f>>1)+8g+4*(f&1)+rg
            f32x4 sf[4] = {};
            #pragma unroll
            for (int f = 0; f < 4; ++f) {
                const int row = f * 16 + lr;
                const int sw = (row & 7) << 4;
                #pragma unroll
                for (int st = 0; st < 4; ++st) {
                    bf16x8 kf = *(const bf16x8*)(Ks + row * 256 + ((st * 64 + g * 16) ^ sw));
                    sf[f] = MFMA_K32(kf, qf[st], sf[f]);
                }
            }
            if (t == nt - 1) {  // boundary tile: causal mask
                const int k0 = t * 64;
                #pragma unroll
                for (int f = 0; f < 4; ++f)
                    #pragma unroll
                    for (int rg = 0; rg < 4; ++rg)
                        if (k0 + 32 * (f >> 1) + 8 * g + 4 * (f & 1) + rg > qr)
                            sf[f][rg] = -1e30f;
            }

            // online softmax (per-lane row qr; g-redundant after shfl reduce)
            float pm = -1e30f;
            #pragma unroll
            for (int f = 0; f < 4; ++f)
                #pragma unroll
                for (int rg = 0; rg < 4; ++rg) pm = fmaxf(pm, sf[f][rg]);
            pm = fmaxf(pm, __shfl_xor(pm, 16));
            pm = fmaxf(pm, __shfl_xor(pm, 32));
            const float mnew = fmaxf(m_r, pm);
            const float corr = __expf(m_r - mnew);
            m_r = mnew;
            float ls = 0.0f;
            bf16x8 plo, phi;
            #pragma unroll
            for (int f = 0; f < 2; ++f)
                #pragma unroll
                for (int rg = 0; rg < 4; ++rg) {
                    float p = __expf(sf[f][rg] - mnew);
                    ls += p;
                    plo[f * 4 + rg] = (short)f2bf(p);
                }
            #pragma unroll
            for (int f = 0; f < 2; ++f)
                #pragma unroll
                for (int rg = 0; rg < 4; ++rg) {
                    float p = __expf(sf[2 + f][rg] - mnew);
                    ls += p;
                    phi[f * 4 + rg] = (short)f2bf(p);
                }
            ls += __shfl_xor(ls, 16);
            ls += __shfl_xor(ls, 32);
            l_r = l_r * corr + ls;

            float cj[4];
            #pragma unroll
            for (int j = 0; j < 4; ++j) cj[j] = __shfl(corr, g * 4 + j);
            #pragma unroll
            for (int db = 0; db < 8; ++db) {
                accO[db][0] *= cj[0]; accO[db][1] *= cj[1];
                accO[db][2] *= cj[2]; accO[db][3] *= cj[3];
            }

            // PV: plo/phi are valid 16x16x32 A-fragments (k = g*8+j)
            #pragma unroll
            for (int db = 0; db < 8; ++db) {
                const int d = db * 16 + lr;
                bf16x8 vlo = *(const bf16x8*)(Vs + d * 128 + ((g ^ (d & 7)) << 4));
                accO[db] = MFMA_K32(plo, vlo, accO[db]);
            }
            #pragma unroll
            for (int db = 0; db < 8; ++db) {
                const int d = db * 16 + lr;
                bf16x8 vhi = *(const bf16x8*)(Vs + d * 128 + (((4 + g) ^ (d & 7)) << 4));
                accO[db] = MFMA_K32(phi, vhi, accO[db]);
            }
        }

        float lj[4];
        #pragma unroll
        for (int j = 0; j < 4; ++j) lj[j] = __shfl(l_r, g * 4 + j);
        #pragma unroll
        for (int j = 0; j < 4; ++j) {
            const int qq = q0 + w * 16 + g * 4 + j;
            const float inv = 1.0f / lj[j];
            unsigned short* dst = Og + ((size_t)(b * S_ + qq)) * D_ + h * HD_;
            #pragma unroll
            for (int db = 0; db < 8; ++db)
                dst[db * 16 + lr] = f2bf(accO[db][j] * inv);
        }
    }
}

extern "C" void kernel_launch(void* const* d_in, const int* in_sizes, int n_in,
                              void* d_out, int out_size, void* d_ws, size_t ws_size,
                              hipStream_t stream) {
    const float* q  = (const float*)d_in[0];
    const float* k  = (const float*)d_in[1];
    const float* v  = (const float*)d_in[2];
    const float* wq = (const float*)d_in[3];
    const float* wk = (const float*)d_in[4];
    const float* wv = (const float*)d_in[5];
    const float* wo = (const float*)d_in[6];

    unsigned short* ws   = (unsigned short*)d_ws;
    unsigned short* wqb  = ws;
    unsigned short* wkb  = wqb + (size_t)D_ * D_;
    unsigned short* wvb  = wkb + (size_t)D_ * D_;
    unsigned short* wob  = wvb + (size_t)D_ * D_;
    unsigned short* xq   = wob + (size_t)D_ * D_;
    unsigned short* xk   = xq + (size_t)B_ * S_ * D_;
    unsigned short* xv   = xk + (size_t)B_ * S_ * D_;
    unsigned short* slot = xv + (size_t)B_ * S_ * D_;  // qb/kb/vb staging, then attn out

    cvt_w4<<<dim3(4096, 4), 256, 0, stream>>>(
        (const float4*)wq, (ushort4*)wqb, (const float4*)wk, (ushort4*)wkb,
        (const float4*)wv, (ushort4*)wvb, (const float4*)wo, (ushort4*)wob);

    cvt_in<<<8192, 256, 0, stream>>>((const float4*)q, (ushort4*)slot);
    gemm_xwt<0><<<512, 256, 0, stream>>>(slot, wqb, xq);
    cvt_in<<<8192, 256, 0, stream>>>((const float4*)k, (ushort4*)slot);
    gemm_xwt<1><<<512, 256, 0, stream>>>(slot, wkb, xk);
    cvt_in<<<8192, 256, 0, stream>>>((const float4*)v, (ushort4*)slot);
    gemm_xwt<2><<<512, 256, 0, stream>>>(slot, wvb, xv);

    attn_fwd<<<512, 256, 0, stream>>>(xq, xk, xv, slot);

    gemm_xwt<3><<<512, 256, 0, stream>>>(slot, wob, d_out);
}